// Round 1
// baseline (634.627 us; speedup 1.0000x reference)
//
#include <hip/hip_runtime.h>
#include <stdint.h>

#define B_   4
#define SQ_  4096
#define SKV_ 4096
#define D_   1024

typedef __attribute__((ext_vector_type(4))) float f32x4;
typedef __attribute__((ext_vector_type(8))) short bf8_t;

__device__ __forceinline__ unsigned short f2bf(float f) {
    unsigned u = __float_as_uint(f);
    u += 0x7fff + ((u >> 16) & 1);   // RNE; inputs are finite
    return (unsigned short)(u >> 16);
}

__device__ __forceinline__ void gload_lds16(const void* g, void* l) {
    __builtin_amdgcn_global_load_lds(
        (const __attribute__((address_space(1))) unsigned int*)g,
        (__attribute__((address_space(3))) unsigned int*)l,
        16, 0, 0);
}

// ---------------- fp32 -> bf16 convert (vectorized) ----------------
__global__ void cvt_f32_bf16_kernel(const float* __restrict__ in,
                                    unsigned short* __restrict__ out, int n4) {
    int stride = gridDim.x * blockDim.x;
    for (int i = blockIdx.x * blockDim.x + threadIdx.x; i < n4; i += stride) {
        float4 v = ((const float4*)in)[i];
        ushort4 o;
        o.x = f2bf(v.x); o.y = f2bf(v.y); o.z = f2bf(v.z); o.w = f2bf(v.w);
        ((ushort4*)out)[i] = o;
    }
}

// ---------------- V [Skv][D] fp32  ->  VT [D][Skv] bf16 ----------------
__global__ void transpose_cvt_kernel(const float* __restrict__ V,
                                     unsigned short* __restrict__ VT) {
    __shared__ float tile[32][33];
    int b = blockIdx.z;
    const float* Vb = V + (size_t)b * SKV_ * D_;
    unsigned short* VTb = VT + (size_t)b * D_ * SKV_;
    int d0 = blockIdx.x * 32, k0 = blockIdx.y * 32;
    int x = threadIdx.x, y = threadIdx.y;   // block (32,8)
    #pragma unroll
    for (int i = 0; i < 4; ++i)
        tile[y + i * 8][x] = Vb[(size_t)(k0 + y + i * 8) * D_ + d0 + x];
    __syncthreads();
    #pragma unroll
    for (int i = 0; i < 4; ++i)
        VTb[(size_t)(d0 + y + i * 8) * SKV_ + k0 + x] = f2bf(tile[x][y + i * 8]);
}

// ---------------- bf16 NT GEMM: C[m][n] = scale * sum_k A[m][k]*B[n][k] (+mask[n]) ----
// m97-style: 128x128 tile, BK=64, 4 waves (2x2), 16x16x32 MFMA, global_load_lds staging
__global__ __launch_bounds__(256, 2) void gemm_nt_bf16_kernel(
    const unsigned short* __restrict__ A, int lda, size_t strideA,
    const unsigned short* __restrict__ Bm, int ldb, size_t strideB,
    float* __restrict__ C, int ldc, size_t strideC,
    int K, float scale, const float* __restrict__ mask)
{
    __shared__ __align__(16) unsigned short As[128 * 64];
    __shared__ __align__(16) unsigned short Bs[128 * 64];
    int b = blockIdx.z;
    const unsigned short* Ab = A + (size_t)b * strideA;
    const unsigned short* Bb = Bm + (size_t)b * strideB;
    float* Cb = C + (size_t)b * strideC;

    int t = threadIdx.x;
    int lane = t & 63, wid = t >> 6;
    int wr = wid >> 1, wc = wid & 1;
    int bm = blockIdx.y, bn = blockIdx.x;

    f32x4 acc[4][4] = {};

    int srow = t >> 3;           // 0..31
    int scol = (t & 7) * 8;      // 0..56
    const unsigned short* ga = Ab + (size_t)(bm * 128 + srow) * lda + scol;
    const unsigned short* gb = Bb + (size_t)(bn * 128 + srow) * ldb + scol;
    char* lA = (char*)As + t * 16;
    char* lB = (char*)Bs + t * 16;

    for (int k0 = 0; k0 < K; k0 += 64) {
        #pragma unroll
        for (int i = 0; i < 4; ++i) {
            gload_lds16(ga + (size_t)(i * 32) * lda + k0, lA + i * 4096);
            gload_lds16(gb + (size_t)(i * 32) * ldb + k0, lB + i * 4096);
        }
        __syncthreads();
        #pragma unroll
        for (int kk = 0; kk < 2; ++kk) {
            bf8_t af[4], bfv[4];
            int ko = kk * 32 + (lane >> 4) * 8;
            #pragma unroll
            for (int i = 0; i < 4; ++i)
                af[i] = *(const bf8_t*)&As[(wr * 64 + i * 16 + (lane & 15)) * 64 + ko];
            #pragma unroll
            for (int j = 0; j < 4; ++j)
                bfv[j] = *(const bf8_t*)&Bs[(wc * 64 + j * 16 + (lane & 15)) * 64 + ko];
            #pragma unroll
            for (int i = 0; i < 4; ++i)
                #pragma unroll
                for (int j = 0; j < 4; ++j)
                    acc[i][j] = __builtin_amdgcn_mfma_f32_16x16x32_bf16(
                        af[i], bfv[j], acc[i][j], 0, 0, 0);
        }
        __syncthreads();
    }

    // C/D layout (m89-verified): col = lane&15, row = (lane>>4)*4 + reg
    int row0 = bm * 128 + wr * 64 + (lane >> 4) * 4;
    int col0 = bn * 128 + wc * 64 + (lane & 15);
    const float* maskb = mask ? mask + (size_t)b * SKV_ : nullptr;
    #pragma unroll
    for (int j = 0; j < 4; ++j) {
        int col = col0 + j * 16;
        float mk = maskb ? maskb[col] : 0.0f;
        #pragma unroll
        for (int i = 0; i < 4; ++i) {
            int row = row0 + i * 16;
            #pragma unroll
            for (int r = 0; r < 4; ++r)
                Cb[(size_t)(row + r) * ldc + col] = acc[i][j][r] * scale + mk;
        }
    }
}

// ---------------- row softmax in place + optional bf16 copy ----------------
__global__ __launch_bounds__(256) void softmax_kernel(float* __restrict__ scores,
                                                      unsigned short* __restrict__ abf) {
    __shared__ __align__(16) float buf[SKV_];
    __shared__ float red[4];
    size_t row = blockIdx.x;
    float* p = scores + row * SKV_;
    int t = threadIdx.x;

    float lmax = -3.4e38f;
    for (int i = t * 4; i < SKV_; i += 1024) {
        float4 v = *(const float4*)(p + i);
        *(float4*)&buf[i] = v;
        lmax = fmaxf(fmaxf(lmax, fmaxf(v.x, v.y)), fmaxf(v.z, v.w));
    }
    #pragma unroll
    for (int o = 32; o; o >>= 1) lmax = fmaxf(lmax, __shfl_down(lmax, o));
    if ((t & 63) == 0) red[t >> 6] = lmax;
    __syncthreads();
    float rmax = fmaxf(fmaxf(red[0], red[1]), fmaxf(red[2], red[3]));
    __syncthreads();

    float lsum = 0.f;
    for (int i = t * 4; i < SKV_; i += 1024) {
        float4 v = *(const float4*)&buf[i];
        v.x = __expf(v.x - rmax); v.y = __expf(v.y - rmax);
        v.z = __expf(v.z - rmax); v.w = __expf(v.w - rmax);
        *(float4*)&buf[i] = v;
        lsum += (v.x + v.y) + (v.z + v.w);
    }
    #pragma unroll
    for (int o = 32; o; o >>= 1) lsum += __shfl_down(lsum, o);
    if ((t & 63) == 0) red[t >> 6] = lsum;
    __syncthreads();
    float rinv = 1.0f / ((red[0] + red[1]) + (red[2] + red[3]));

    unsigned short* ab = abf ? abf + row * SKV_ : nullptr;
    for (int i = t * 4; i < SKV_; i += 1024) {
        float4 v = *(const float4*)&buf[i];
        v.x *= rinv; v.y *= rinv; v.z *= rinv; v.w *= rinv;
        *(float4*)(p + i) = v;
        if (ab) {
            ushort4 o;
            o.x = f2bf(v.x); o.y = f2bf(v.y); o.z = f2bf(v.z); o.w = f2bf(v.w);
            *(ushort4*)(ab + i) = o;
        }
    }
}

// ---------------- naive fallback path (used only if ws too small) ----------------
__global__ void naive_nt_kernel(const float* __restrict__ A, const float* __restrict__ Bm,
                                float* __restrict__ C, const float* __restrict__ mask,
                                int N, int K, float scale) {
    __shared__ float As[16][16], Bs[16][16];
    int b = blockIdx.z;
    const float* Ab = A + (size_t)b * SQ_ * K;
    const float* Bb = Bm + (size_t)b * N * K;
    float* Cb = C + (size_t)b * SQ_ * N;
    int tx = threadIdx.x, ty = threadIdx.y;
    int m = blockIdx.y * 16 + ty, n = blockIdx.x * 16 + tx;
    float acc = 0.f;
    for (int k0 = 0; k0 < K; k0 += 16) {
        As[ty][tx] = Ab[(size_t)m * K + k0 + tx];
        Bs[ty][tx] = Bb[(size_t)(blockIdx.x * 16 + ty) * K + k0 + tx];
        __syncthreads();
        #pragma unroll
        for (int kk = 0; kk < 16; ++kk) acc += As[ty][kk] * Bs[tx][kk];
        __syncthreads();
    }
    Cb[(size_t)m * N + n] = acc * scale + (mask ? mask[(size_t)b * SKV_ + n] : 0.f);
}

__global__ void naive_nn_kernel(const float* __restrict__ A, const float* __restrict__ Bm,
                                float* __restrict__ C, int N, int K) {
    __shared__ float As[16][16], Bs[16][17];
    int b = blockIdx.z;
    const float* Ab = A + (size_t)b * SQ_ * K;
    const float* Bb = Bm + (size_t)b * K * N;
    float* Cb = C + (size_t)b * SQ_ * N;
    int tx = threadIdx.x, ty = threadIdx.y;
    int m = blockIdx.y * 16 + ty, n = blockIdx.x * 16 + tx;
    float acc = 0.f;
    for (int k0 = 0; k0 < K; k0 += 16) {
        As[ty][tx] = Ab[(size_t)m * K + k0 + tx];
        Bs[ty][tx] = Bb[(size_t)(k0 + ty) * N + n];
        __syncthreads();
        #pragma unroll
        for (int kk = 0; kk < 16; ++kk) acc += As[ty][kk] * Bs[kk][tx];
        __syncthreads();
    }
    Cb[(size_t)m * N + n] = acc;
}

extern "C" void kernel_launch(void* const* d_in, const int* in_sizes, int n_in,
                              void* d_out, int out_size, void* d_ws, size_t ws_size,
                              hipStream_t stream) {
    const float* q    = (const float*)d_in[0];
    const float* kv   = (const float*)d_in[1];
    const float* mask = (const float*)d_in[2];
    // d_in[3] = layer_idx: compression rate 1.0 at layer 0 -> identity, unused.

    float* out  = (float*)d_out;
    float* attn = out + (size_t)B_ * SQ_ * D_;   // outputs: (out, attn) concatenated
    const float scale = 0.03125f;                // 1/sqrt(1024)

    size_t nQ    = (size_t)B_ * SQ_ * D_;
    size_t nKV   = (size_t)B_ * SKV_ * D_;
    size_t nAttn = (size_t)B_ * SQ_ * SKV_;
    size_t need  = (nQ + nKV + nKV + nAttn) * 2;   // qbf + kbf + vtbf + abf

    if (ws_size >= need) {
        unsigned short* qbf  = (unsigned short*)d_ws;
        unsigned short* kbf  = qbf + nQ;
        unsigned short* vtbf = kbf + nKV;
        unsigned short* abf  = vtbf + nKV;

        cvt_f32_bf16_kernel<<<2048, 256, 0, stream>>>(q, qbf, (int)(nQ / 4));
        cvt_f32_bf16_kernel<<<2048, 256, 0, stream>>>(kv, kbf, (int)(nKV / 4));
        transpose_cvt_kernel<<<dim3(D_ / 32, SKV_ / 32, B_), dim3(32, 8), 0, stream>>>(kv, vtbf);

        // scores = scale * Q K^T + mask  (raw, pre-softmax) into attn region
        gemm_nt_bf16_kernel<<<dim3(SKV_ / 128, SQ_ / 128, B_), 256, 0, stream>>>(
            qbf, D_, (size_t)SQ_ * D_,
            kbf, D_, (size_t)SKV_ * D_,
            attn, SKV_, (size_t)SQ_ * SKV_,
            D_, scale, mask);

        softmax_kernel<<<B_ * SQ_, 256, 0, stream>>>(attn, abf);

        // out = attn @ V  ==  NT gemm with B = V^T  [D][Skv]
        gemm_nt_bf16_kernel<<<dim3(D_ / 128, SQ_ / 128, B_), 256, 0, stream>>>(
            abf, SKV_, (size_t)SQ_ * SKV_,
            vtbf, SKV_, (size_t)D_ * SKV_,
            out, D_, (size_t)SQ_ * D_,
            SKV_, 1.0f, nullptr);
    } else {
        // insurance path: no scratch required
        naive_nt_kernel<<<dim3(SKV_ / 16, SQ_ / 16, B_), dim3(16, 16), 0, stream>>>(
            q, kv, attn, mask, SKV_, D_, scale);
        softmax_kernel<<<B_ * SQ_, 256, 0, stream>>>(attn, nullptr);
        naive_nn_kernel<<<dim3(D_ / 16, SQ_ / 16, B_), dim3(16, 16), 0, stream>>>(
            attn, kv, out, D_, SKV_);
    }
}

// Round 2
// 533.447 us; speedup vs baseline: 1.1897x; 1.1897x over previous
//
#include <hip/hip_runtime.h>
#include <stdint.h>

#define B_   4
#define SQ_  4096
#define SKV_ 4096
#define D_   1024

typedef __attribute__((ext_vector_type(4))) float f32x4;
typedef __attribute__((ext_vector_type(8))) short bf8_t;

__device__ __forceinline__ unsigned short f2bf(float f) {
    unsigned u = __float_as_uint(f);
    u += 0x7fff + ((u >> 16) & 1);   // RNE; inputs are finite
    return (unsigned short)(u >> 16);
}

__device__ __forceinline__ void gload_lds16(const void* g, void* l) {
    __builtin_amdgcn_global_load_lds(
        (const __attribute__((address_space(1))) unsigned int*)g,
        (__attribute__((address_space(3))) unsigned int*)l,
        16, 0, 0);
}

__device__ __forceinline__ void barrier_mem() {
    asm volatile("" ::: "memory");
    __builtin_amdgcn_s_barrier();
    asm volatile("" ::: "memory");
}

// ---------------- fp32 -> bf16 convert (vectorized) ----------------
__global__ void cvt_f32_bf16_kernel(const float* __restrict__ in,
                                    unsigned short* __restrict__ out, int n4) {
    int stride = gridDim.x * blockDim.x;
    for (int i = blockIdx.x * blockDim.x + threadIdx.x; i < n4; i += stride) {
        float4 v = ((const float4*)in)[i];
        ushort4 o;
        o.x = f2bf(v.x); o.y = f2bf(v.y); o.z = f2bf(v.z); o.w = f2bf(v.w);
        ((ushort4*)out)[i] = o;
    }
}

// ---------------- V [Skv][D] fp32  ->  VT [D][Skv] bf16 ----------------
__global__ void transpose_cvt_kernel(const float* __restrict__ V,
                                     unsigned short* __restrict__ VT) {
    __shared__ float tile[32][33];
    int b = blockIdx.z;
    const float* Vb = V + (size_t)b * SKV_ * D_;
    unsigned short* VTb = VT + (size_t)b * D_ * SKV_;
    int d0 = blockIdx.x * 32, k0 = blockIdx.y * 32;
    int x = threadIdx.x, y = threadIdx.y;   // block (32,8)
    #pragma unroll
    for (int i = 0; i < 4; ++i)
        tile[y + i * 8][x] = Vb[(size_t)(k0 + y + i * 8) * D_ + d0 + x];
    __syncthreads();
    #pragma unroll
    for (int i = 0; i < 4; ++i)
        VTb[(size_t)(d0 + y + i * 8) * SKV_ + k0 + x] = f2bf(tile[x][y + i * 8]);
}

// ================= 256x256 8-phase bf16 NT GEMM (m201-style template) ==========
// C[m][n] = scale * sum_k A[m][k]*B[n][k] (+ mask[n]).  BK=64, 8 waves (2Mx4N),
// LDS 128 KiB = 2 dbuf x {A,B} x 2 K-halves x (256 rows x 32 k x bf16).
// Per K-tile: 4 phases, each {ds_read subtile | stage 1 half-tile | bar |
// setprio(1) 16 MFMA setprio(0) | bar}; counted vmcnt(6) once per tile.
// LDS XOR swizzle col^=((r&3)^((r>>2)&3))<<4 applied on BOTH global-source
// (stage) and ds_read sides; LDS writes stay linear for global_load_lds.
__global__ __launch_bounds__(512, 2) void gemm256_nt_bf16_kernel(
    const unsigned short* __restrict__ A, int lda, size_t strideA,
    const unsigned short* __restrict__ Bm, int ldb, size_t strideB,
    float* __restrict__ C, int ldc, size_t strideC,
    int K, float scale, const float* __restrict__ mask)
{
    __shared__ __align__(16) unsigned char smem[131072];

    const int tid  = threadIdx.x;
    const int lane = tid & 63, wid = tid >> 6;
    const int wr = wid >> 2, wc = wid & 3;       // 2 M-halves x 4 N-quarters

    // bijective XCD swizzle (gridDim.x*gridDim.y divisible by 8 here)
    int lin  = blockIdx.y * gridDim.x + blockIdx.x;
    int q    = (gridDim.x * gridDim.y) >> 3;
    int lin2 = (lin & 7) * q + (lin >> 3);
    int bn = lin2 % gridDim.x, bm = lin2 / gridDim.x;
    int bz = blockIdx.z;

    const char* Ab = (const char*)(A + (size_t)bz * strideA);
    const char* Bb = (const char*)(Bm + (size_t)bz * strideB);
    float* Cb = C + (size_t)bz * strideC;
    const int ldaB = lda * 2, ldbB = ldb * 2;

    // ---- staging per-thread constants (inverse-swizzled global source) ----
    // thread t, load j in {0,1}: covers LDS phys (r = j*128 + t>>2, cb = (t&3)*16)
    const int colSwz = ((tid & 3) * 16) ^ ((((tid >> 2) & 3) ^ ((tid >> 4) & 3)) << 4);
    const char* Apan = Ab + (size_t)(bm * 256 + (tid >> 2)) * ldaB + colSwz;
    const char* Bpan = Bb + (size_t)(bn * 256 + (tid >> 2)) * ldbB + colSwz;
    char* ldsA = (char*)smem;            // [buf][half]: 2 x 2 x 16 KiB
    char* ldsB = (char*)smem + 65536;

    // ---- fragment-read per-thread constants (swizzled ds_read address) ----
    const int rdOff = ((lane & 15) * 64) +
                      (((lane >> 4) * 16) ^ ((((lane & 3) ^ ((lane >> 2) & 3))) << 4));
    const char* aRd = (char*)smem + wr * 8192 + rdOff;
    const char* bRd = (char*)smem + 65536 + wc * 4096 + rdOff;

    f32x4 acc[8][4] = {};
    const int NT = K >> 6;

#define STAGE_A(tt, hh) do { \
    const char* s_ = Apan + (tt) * 128 + (hh) * 64; \
    char* d_ = ldsA + (((tt) & 1) * 32768) + (hh) * 16384 + tid * 16; \
    gload_lds16(s_, d_); \
    gload_lds16(s_ + (size_t)128 * ldaB, d_ + 8192); \
} while (0)
#define STAGE_B(tt, hh) do { \
    const char* s_ = Bpan + (tt) * 128 + (hh) * 64; \
    char* d_ = ldsB + (((tt) & 1) * 32768) + (hh) * 16384 + tid * 16; \
    gload_lds16(s_, d_); \
    gload_lds16(s_ + (size_t)128 * ldbB, d_ + 8192); \
} while (0)

    // ---- prologue: tile0 complete + 3 halves of tile1; drain to 6 in flight ----
    STAGE_A(0, 0); STAGE_A(0, 1); STAGE_B(0, 0); STAGE_B(0, 1);
    if (NT > 1) {
        STAGE_A(1, 0); STAGE_B(1, 0); STAGE_B(1, 1);
        asm volatile("s_waitcnt vmcnt(6)" ::: "memory");
    } else {
        asm volatile("s_waitcnt vmcnt(0)" ::: "memory");
    }
    barrier_mem();

    for (int t = 0; t < NT; ++t) {
        const int p = t & 1;
        const char* aT = aRd + p * 32768;
        const char* bT = bRd + p * 32768;
        bf8_t a0[8], a1[8], b0[4], b1[4];

        // -------- phase 1: read A(kk0) x8 + B(kk0) x4; stage Ah1(t+1) --------
        #pragma unroll
        for (int m = 0; m < 8; ++m) a0[m] = *(const bf8_t*)(aT + m * 1024);
        #pragma unroll
        for (int n = 0; n < 4; ++n) b0[n] = *(const bf8_t*)(bT + n * 1024);
        if (t + 1 < NT) STAGE_A(t + 1, 1);
        barrier_mem();
        __builtin_amdgcn_s_setprio(1);
        #pragma unroll
        for (int m = 0; m < 4; ++m)
            #pragma unroll
            for (int n = 0; n < 4; ++n)
                acc[m][n] = __builtin_amdgcn_mfma_f32_16x16x32_bf16(a0[m], b0[n], acc[m][n], 0, 0, 0);
        __builtin_amdgcn_s_setprio(0);
        barrier_mem();

        // -------- phase 2: read B(kk1) x4; stage Ah0(t+2) --------
        #pragma unroll
        for (int n = 0; n < 4; ++n) b1[n] = *(const bf8_t*)(bT + 16384 + n * 1024);
        if (t + 2 < NT) STAGE_A(t + 2, 0);
        barrier_mem();
        __builtin_amdgcn_s_setprio(1);
        #pragma unroll
        for (int m = 0; m < 4; ++m)
            #pragma unroll
            for (int n = 0; n < 4; ++n)
                acc[m + 4][n] = __builtin_amdgcn_mfma_f32_16x16x32_bf16(a0[m + 4], b0[n], acc[m + 4][n], 0, 0, 0);
        __builtin_amdgcn_s_setprio(0);
        barrier_mem();

        // -------- phase 3: read A(kk1) x8; stage Bh0(t+2) --------
        #pragma unroll
        for (int m = 0; m < 8; ++m) a1[m] = *(const bf8_t*)(aT + 16384 + m * 1024);
        if (t + 2 < NT) STAGE_B(t + 2, 0);
        barrier_mem();
        __builtin_amdgcn_s_setprio(1);
        #pragma unroll
        for (int m = 0; m < 4; ++m)
            #pragma unroll
            for (int n = 0; n < 4; ++n)
                acc[m][n] = __builtin_amdgcn_mfma_f32_16x16x32_bf16(a1[m], b1[n], acc[m][n], 0, 0, 0);
        __builtin_amdgcn_s_setprio(0);
        barrier_mem();

        // -------- phase 4: stage Bh1(t+2); counted vmcnt once per tile --------
        if (t + 2 < NT) STAGE_B(t + 2, 1);
        barrier_mem();
        __builtin_amdgcn_s_setprio(1);
        #pragma unroll
        for (int m = 0; m < 4; ++m)
            #pragma unroll
            for (int n = 0; n < 4; ++n)
                acc[m + 4][n] = __builtin_amdgcn_mfma_f32_16x16x32_bf16(a1[m + 4], b1[n], acc[m + 4][n], 0, 0, 0);
        __builtin_amdgcn_s_setprio(0);
        if (t + 2 < NT)      asm volatile("s_waitcnt vmcnt(6)" ::: "memory");
        else if (t + 1 < NT) asm volatile("s_waitcnt vmcnt(0)" ::: "memory");
        barrier_mem();
    }
#undef STAGE_A
#undef STAGE_B

    // ---- epilogue: C/D layout col=lane&15, row=(lane>>4)*4+reg ----
    const int row0 = bm * 256 + wr * 128 + (lane >> 4) * 4;
    const int col0 = bn * 256 + wc * 64 + (lane & 15);
    const float* maskb = mask ? mask + (size_t)bz * SKV_ : nullptr;
    #pragma unroll
    for (int n = 0; n < 4; ++n) {
        int col = col0 + n * 16;
        float mk = maskb ? maskb[col] : 0.0f;
        #pragma unroll
        for (int m = 0; m < 8; ++m) {
            int row = row0 + m * 16;
            #pragma unroll
            for (int r = 0; r < 4; ++r)
                Cb[(size_t)(row + r) * ldc + col] = acc[m][n][r] * scale + mk;
        }
    }
}

// ---------------- row softmax in place + optional bf16 copy ----------------
__global__ __launch_bounds__(256) void softmax_kernel(float* __restrict__ scores,
                                                      unsigned short* __restrict__ abf) {
    __shared__ __align__(16) float buf[SKV_];
    __shared__ float red[4];
    size_t row = blockIdx.x;
    float* p = scores + row * SKV_;
    int t = threadIdx.x;

    float lmax = -3.4e38f;
    for (int i = t * 4; i < SKV_; i += 1024) {
        float4 v = *(const float4*)(p + i);
        *(float4*)&buf[i] = v;
        lmax = fmaxf(fmaxf(lmax, fmaxf(v.x, v.y)), fmaxf(v.z, v.w));
    }
    #pragma unroll
    for (int o = 32; o; o >>= 1) lmax = fmaxf(lmax, __shfl_down(lmax, o));
    if ((t & 63) == 0) red[t >> 6] = lmax;
    __syncthreads();
    float rmax = fmaxf(fmaxf(red[0], red[1]), fmaxf(red[2], red[3]));
    __syncthreads();

    float lsum = 0.f;
    for (int i = t * 4; i < SKV_; i += 1024) {
        float4 v = *(const float4*)&buf[i];
        v.x = __expf(v.x - rmax); v.y = __expf(v.y - rmax);
        v.z = __expf(v.z - rmax); v.w = __expf(v.w - rmax);
        *(float4*)&buf[i] = v;
        lsum += (v.x + v.y) + (v.z + v.w);
    }
    #pragma unroll
    for (int o = 32; o; o >>= 1) lsum += __shfl_down(lsum, o);
    if ((t & 63) == 0) red[t >> 6] = lsum;
    __syncthreads();
    float rinv = 1.0f / ((red[0] + red[1]) + (red[2] + red[3]));

    unsigned short* ab = abf ? abf + row * SKV_ : nullptr;
    for (int i = t * 4; i < SKV_; i += 1024) {
        float4 v = *(const float4*)&buf[i];
        v.x *= rinv; v.y *= rinv; v.z *= rinv; v.w *= rinv;
        *(float4*)(p + i) = v;
        if (ab) {
            ushort4 o;
            o.x = f2bf(v.x); o.y = f2bf(v.y); o.z = f2bf(v.z); o.w = f2bf(v.w);
            *(ushort4*)(ab + i) = o;
        }
    }
}

// ---------------- naive fallback path (used only if ws too small) ----------------
__global__ void naive_nt_kernel(const float* __restrict__ A, const float* __restrict__ Bm,
                                float* __restrict__ C, const float* __restrict__ mask,
                                int N, int K, float scale) {
    __shared__ float As[16][16], Bs[16][16];
    int b = blockIdx.z;
    const float* Ab = A + (size_t)b * SQ_ * K;
    const float* Bb = Bm + (size_t)b * N * K;
    float* Cb = C + (size_t)b * SQ_ * N;
    int tx = threadIdx.x, ty = threadIdx.y;
    int m = blockIdx.y * 16 + ty, n = blockIdx.x * 16 + tx;
    float acc = 0.f;
    for (int k0 = 0; k0 < K; k0 += 16) {
        As[ty][tx] = Ab[(size_t)m * K + k0 + tx];
        Bs[ty][tx] = Bb[(size_t)(blockIdx.x * 16 + ty) * K + k0 + tx];
        __syncthreads();
        #pragma unroll
        for (int kk = 0; kk < 16; ++kk) acc += As[ty][kk] * Bs[tx][kk];
        __syncthreads();
    }
    Cb[(size_t)m * N + n] = acc * scale + (mask ? mask[(size_t)b * SKV_ + n] : 0.f);
}

__global__ void naive_nn_kernel(const float* __restrict__ A, const float* __restrict__ Bm,
                                float* __restrict__ C, int N, int K) {
    __shared__ float As[16][16], Bs[16][17];
    int b = blockIdx.z;
    const float* Ab = A + (size_t)b * SQ_ * K;
    const float* Bb = Bm + (size_t)b * K * N;
    float* Cb = C + (size_t)b * SQ_ * N;
    int tx = threadIdx.x, ty = threadIdx.y;
    int m = blockIdx.y * 16 + ty, n = blockIdx.x * 16 + tx;
    float acc = 0.f;
    for (int k0 = 0; k0 < K; k0 += 16) {
        As[ty][tx] = Ab[(size_t)m * K + k0 + tx];
        Bs[ty][tx] = Bb[(size_t)(k0 + ty) * N + n];
        __syncthreads();
        #pragma unroll
        for (int kk = 0; kk < 16; ++kk) acc += As[ty][kk] * Bs[kk][tx];
        __syncthreads();
    }
    Cb[(size_t)m * N + n] = acc;
}

extern "C" void kernel_launch(void* const* d_in, const int* in_sizes, int n_in,
                              void* d_out, int out_size, void* d_ws, size_t ws_size,
                              hipStream_t stream) {
    const float* q    = (const float*)d_in[0];
    const float* kv   = (const float*)d_in[1];
    const float* mask = (const float*)d_in[2];
    // d_in[3] = layer_idx: compression rate 1.0 at layer 0 -> identity, unused.

    float* out  = (float*)d_out;
    float* attn = out + (size_t)B_ * SQ_ * D_;   // outputs: (out, attn) concatenated
    const float scale = 0.03125f;                // 1/sqrt(1024)

    size_t nQ    = (size_t)B_ * SQ_ * D_;
    size_t nKV   = (size_t)B_ * SKV_ * D_;
    size_t nAttn = (size_t)B_ * SQ_ * SKV_;
    size_t need  = (nQ + nKV + nKV + nAttn) * 2;   // qbf + kbf + vtbf + abf

    if (ws_size >= need) {
        unsigned short* qbf  = (unsigned short*)d_ws;
        unsigned short* kbf  = qbf + nQ;
        unsigned short* vtbf = kbf + nKV;
        unsigned short* abf  = vtbf + nKV;

        cvt_f32_bf16_kernel<<<2048, 256, 0, stream>>>(q, qbf, (int)(nQ / 4));
        cvt_f32_bf16_kernel<<<2048, 256, 0, stream>>>(kv, kbf, (int)(nKV / 4));
        transpose_cvt_kernel<<<dim3(D_ / 32, SKV_ / 32, B_), dim3(32, 8), 0, stream>>>(kv, vtbf);

        // scores = scale * Q K^T + mask  (raw, pre-softmax) into attn region
        gemm256_nt_bf16_kernel<<<dim3(SKV_ / 256, SQ_ / 256, B_), 512, 0, stream>>>(
            qbf, D_, (size_t)SQ_ * D_,
            kbf, D_, (size_t)SKV_ * D_,
            attn, SKV_, (size_t)SQ_ * SKV_,
            D_, scale, mask);

        softmax_kernel<<<B_ * SQ_, 256, 0, stream>>>(attn, abf);

        // out = attn @ V  ==  NT gemm with B = V^T  [D][Skv]
        gemm256_nt_bf16_kernel<<<dim3(D_ / 256, SQ_ / 256, B_), 512, 0, stream>>>(
            abf, SKV_, (size_t)SQ_ * SKV_,
            vtbf, SKV_, (size_t)D_ * SKV_,
            out, D_, (size_t)SQ_ * D_,
            SKV_, 1.0f, nullptr);
    } else {
        // insurance path: no scratch required
        naive_nt_kernel<<<dim3(SKV_ / 16, SQ_ / 16, B_), dim3(16, 16), 0, stream>>>(
            q, kv, attn, mask, SKV_, D_, scale);
        softmax_kernel<<<B_ * SQ_, 256, 0, stream>>>(attn, nullptr);
        naive_nn_kernel<<<dim3(D_ / 16, SQ_ / 16, B_), dim3(16, 16), 0, stream>>>(
            attn, kv, out, D_, SKV_);
    }
}